// Round 1
// baseline (4076.594 us; speedup 1.0000x reference)
//
#include <hip/hip_runtime.h>
#include <hip/hip_bf16.h>

#define TT 2048
#define BB 256
#define HH 64
#define OO 12

__device__ __forceinline__ float rl(float v, int k) {
  return __uint_as_float(__builtin_amdgcn_readlane(__float_as_uint(v), k));
}
__device__ __forceinline__ float sigf(float x)   { return 1.f / (1.f + __expf(-x)); }
__device__ __forceinline__ float tanhf2(float x) { return 2.f / (1.f + __expf(-2.f * x)) - 1.f; }

// gate pre-activation for this thread's gate: bias + x.Wih_col + h.Whh_col
template<int IN>
__device__ __forceinline__ float gates(float xv, float h,
                                       const float* wih, const float* whh, float bias) {
  float a0 = bias, a1 = 0.f, a2 = 0.f, a3 = 0.f;
#pragma unroll
  for (int k = 0; k < IN; k += 4) {
    a0 += rl(xv, k + 0) * wih[k + 0];
    a1 += rl(xv, k + 1) * wih[k + 1];
    a2 += rl(xv, k + 2) * wih[k + 2];
    a3 += rl(xv, k + 3) * wih[k + 3];
  }
#pragma unroll
  for (int k = 0; k < HH; k += 4) {
    a0 += rl(h, k + 0) * whh[k + 0];
    a1 += rl(h, k + 1) * whh[k + 1];
    a2 += rl(h, k + 2) * whh[k + 2];
    a3 += rl(h, k + 3) * whh[k + 3];
  }
  return (a0 + a1) + (a2 + a3);
}

// One block per batch element. 256 threads = 4 waves; thread j owns gate j
// (wave 0 = i, 1 = f, 2 = g~, 3 = o, lane = hidden unit). Weights live in VGPRs.
// All waves redundantly combine gates so h,c stay in-lane per wave (readlane feed).
template<int IN, bool L0, bool BF>
__global__ __launch_bounds__(256, 1)
void lstm_layer(const void* __restrict__ xin_v,
                void* __restrict__ hs_v,
                const float* __restrict__ Wih,
                const float* __restrict__ Whh,
                const float* __restrict__ bih,
                const float* __restrict__ bhh,
                const float* __restrict__ h0,
                const float* __restrict__ c0,
                float* __restrict__ hn,
                float* __restrict__ cn) {
  const int b    = blockIdx.x;
  const int tid  = threadIdx.x;
  const int lane = tid & 63;

  __shared__ float gbuf[2][256];

  float wih[IN], whh[HH];
#pragma unroll
  for (int k = 0; k < IN; k++) wih[k] = Wih[tid * IN + k];
#pragma unroll
  for (int k = 0; k < HH; k++) whh[k] = Whh[tid * HH + k];
  const float bias = bih[tid] + bhh[tid];

  float h = h0[b * HH + lane];
  float c = c0[b * HH + lane];

  const float*          xf = nullptr;
  const __hip_bfloat16* xb = nullptr;
  if (L0)      xf = (const float*)xin_v + (size_t)b * TT * IN + lane;
  else if (BF) xb = (const __hip_bfloat16*)xin_v + (size_t)b * HH + lane;
  else         xf = (const float*)xin_v + (size_t)b * HH + lane;

  float*          hsf = (float*)hs_v + (size_t)b * HH + lane;
  __hip_bfloat16* hsb = (__hip_bfloat16*)hs_v + (size_t)b * HH + lane;

  auto loadx = [&](int t) -> float {
    if (L0)      return (lane < IN) ? xf[(size_t)t * IN] : 0.f;
    else if (BF) return __bfloat162float(xb[(size_t)t * (BB * HH)]);
    else         return xf[(size_t)t * (BB * HH)];
  };

  // Rotated pipeline: gbuf[t&1] holds gates for step t when iteration t begins.
  float x0 = loadx(0);
  float xv = loadx(1);  // input for gates(t=1), computed during iteration 0
  gbuf[0][tid] = gates<IN>(x0, h, wih, whh, bias);
  __syncthreads();

  for (int t = 0; t < TT; t++) {
    const int p = t & 1;
    float gi = gbuf[p][lane];
    float gf = gbuf[p][lane + 64];
    float gg = gbuf[p][lane + 128];
    float go = gbuf[p][lane + 192];

    float xn = (t + 2 < TT) ? loadx(t + 2) : 0.f;  // prefetch

    // combine (serial transcendental chain; overlaps with next step's x-part FMAs)
    c = sigf(gf) * c + sigf(gi) * tanhf2(gg);
    h = sigf(go) * tanhf2(c);

    if (t + 1 < TT)
      gbuf[p ^ 1][tid] = gates<IN>(xv, h, wih, whh, bias);

    if (tid < 64) {
      if (BF) hsb[(size_t)t * (BB * HH)] = __float2bfloat16(h);
      else    hsf[(size_t)t * (BB * HH)] = h;
    }
    xv = xn;
    __syncthreads();
  }

  if (tid < 64) {
    hn[b * HH + lane] = h;
    cn[b * HH + lane] = c;
  }
}

// y[b,t,:] = W_out @ hs[t,b,:] + b_out. One thread per (t,b) row.
template<bool BF>
__global__ __launch_bounds__(256, 1)
void out_proj(const void* __restrict__ hs_v,
              const float* __restrict__ Wout,
              const float* __restrict__ bout,
              float* __restrict__ y) {
  const int g = blockIdx.x * 256 + threadIdx.x;  // g = t*256 + b
  const int t = g >> 8;
  const int b = g & 255;

  float hrow[HH];
  if (BF) {
    const __hip_bfloat16* r = (const __hip_bfloat16*)hs_v + (size_t)g * HH;
#pragma unroll
    for (int k = 0; k < HH; k++) hrow[k] = __bfloat162float(r[k]);
  } else {
    const float* r = (const float*)hs_v + (size_t)g * HH;
#pragma unroll
    for (int k = 0; k < HH; k++) hrow[k] = r[k];
  }

  float* yp = y + (size_t)b * TT * OO + (size_t)t * OO;
#pragma unroll
  for (int o = 0; o < OO; o++) {
    float a0 = bout[o], a1 = 0.f, a2 = 0.f, a3 = 0.f;
#pragma unroll
    for (int k = 0; k < HH; k += 4) {
      a0 += hrow[k + 0] * Wout[o * HH + k + 0];
      a1 += hrow[k + 1] * Wout[o * HH + k + 1];
      a2 += hrow[k + 2] * Wout[o * HH + k + 2];
      a3 += hrow[k + 3] * Wout[o * HH + k + 3];
    }
    yp[o] = (a0 + a1) + (a2 + a3);
  }
}

extern "C" void kernel_launch(void* const* d_in, const int* in_sizes, int n_in,
                              void* d_out, int out_size, void* d_ws, size_t ws_size,
                              hipStream_t stream) {
  const float* x    = (const float*)d_in[0];
  const float* h0   = (const float*)d_in[1];
  const float* c0   = (const float*)d_in[2];
  const float* Wih0 = (const float*)d_in[3];
  const float* Whh0 = (const float*)d_in[4];
  const float* bih0 = (const float*)d_in[5];
  const float* bhh0 = (const float*)d_in[6];
  const float* Wih1 = (const float*)d_in[7];
  const float* Whh1 = (const float*)d_in[8];
  const float* bih1 = (const float*)d_in[9];
  const float* bhh1 = (const float*)d_in[10];
  const float* Wih2 = (const float*)d_in[11];
  const float* Whh2 = (const float*)d_in[12];
  const float* bih2 = (const float*)d_in[13];
  const float* bhh2 = (const float*)d_in[14];
  const float* Wout = (const float*)d_in[15];
  const float* bout = (const float*)d_in[16];

  float* y  = (float*)d_out;
  float* hn = y + (size_t)BB * TT * OO;
  float* cn = hn + (size_t)3 * BB * HH;

  const size_t needF = (size_t)TT * BB * HH * sizeof(float);
  const bool   bf    = ws_size < needF;  // bf16 hs fallback if scratch is tight
  void* hs = d_ws;

  dim3 grid(BB), blk(256);
  dim3 ygrid(TT * BB / 256);

  if (!bf) {
    lstm_layer<60, true,  false><<<grid, blk, 0, stream>>>(x,  hs, Wih0, Whh0, bih0, bhh0,
        h0 + 0 * BB * HH, c0 + 0 * BB * HH, hn + 0 * BB * HH, cn + 0 * BB * HH);
    lstm_layer<64, false, false><<<grid, blk, 0, stream>>>(hs, hs, Wih1, Whh1, bih1, bhh1,
        h0 + 1 * BB * HH, c0 + 1 * BB * HH, hn + 1 * BB * HH, cn + 1 * BB * HH);
    lstm_layer<64, false, false><<<grid, blk, 0, stream>>>(hs, hs, Wih2, Whh2, bih2, bhh2,
        h0 + 2 * BB * HH, c0 + 2 * BB * HH, hn + 2 * BB * HH, cn + 2 * BB * HH);
    out_proj<false><<<ygrid, blk, 0, stream>>>(hs, Wout, bout, y);
  } else {
    lstm_layer<60, true,  true><<<grid, blk, 0, stream>>>(x,  hs, Wih0, Whh0, bih0, bhh0,
        h0 + 0 * BB * HH, c0 + 0 * BB * HH, hn + 0 * BB * HH, cn + 0 * BB * HH);
    lstm_layer<64, false, true><<<grid, blk, 0, stream>>>(hs, hs, Wih1, Whh1, bih1, bhh1,
        h0 + 1 * BB * HH, c0 + 1 * BB * HH, hn + 1 * BB * HH, cn + 1 * BB * HH);
    lstm_layer<64, false, true><<<grid, blk, 0, stream>>>(hs, hs, Wih2, Whh2, bih2, bhh2,
        h0 + 2 * BB * HH, c0 + 2 * BB * HH, hn + 2 * BB * HH, cn + 2 * BB * HH);
    out_proj<true><<<ygrid, blk, 0, stream>>>(hs, Wout, bout, y);
  }
}